// Round 1
// 408.147 us; speedup vs baseline: 1.0059x; 1.0059x over previous
//
#include <hip/hip_runtime.h>

#define T 4096
#define B 64
#define D 256

// Kernel A: per-batch doc search + gather + linear0 (x = g @ W0^T + b0), gate.
// 64 blocks x 256 threads. Tiny (~1MB exe scan + 64KB W0 per block from L2).
__global__ __launch_bounds__(256) void prep_kernel(
    const int* __restrict__ batch_nodes, const int* __restrict__ exe,
    const float* __restrict__ graph_dict, const float* __restrict__ W0,
    const float* __restrict__ b0, float* __restrict__ x_ws,
    float* __restrict__ gate_out)
{
    const int b   = blockIdx.x;
    const int tid = threadIdx.x;

    // last t with exe[b,t]==1 — int4-vectorized scan (4 iterations of 256 thr).
    // q ascending per thread and x<y<z<w within int4, so overwrite == max.
    int best = -1;
    const int4* erow4 = (const int4*)(exe + (size_t)b * T);
    for (int q = tid; q < T / 4; q += 256) {
        int4 v = erow4[q];
        const int t = q * 4;
        if (v.x == 1) best = t;
        if (v.y == 1) best = t + 1;
        if (v.z == 1) best = t + 2;
        if (v.w == 1) best = t + 3;
    }

    for (int off = 32; off > 0; off >>= 1) {
        int o = __shfl_down(best, off, 64);
        best = best > o ? best : o;
    }
    __shared__ int sred[4];
    __shared__ int s_doc;
    const int wid = tid >> 6, lane = tid & 63;
    if (lane == 0) sred[wid] = best;
    __syncthreads();
    if (tid == 0) {
        int m = sred[0];
        if (sred[1] > m) m = sred[1];
        if (sred[2] > m) m = sred[2];
        if (sred[3] > m) m = sred[3];
        s_doc = m;
    }
    __syncthreads();

    const int  doc  = s_doc;
    const bool has  = doc >= 0;
    const int  safe = has ? doc : 0;
    const int  node = batch_nodes[(size_t)b * T + safe];

    __shared__ float s_g[D];
    s_g[tid] = has ? graph_dict[(size_t)node * D + tid] : 0.0f;
    __syncthreads();

    // x[b,e] = b0[e] + sum_d g[d] * W0[e,d]   (when !has: x = b0 — bias stays!)
    const int e = tid;
    const float4* wrow = (const float4*)(W0 + (size_t)e * D);
    float acc = b0[e];
    #pragma unroll 8
    for (int d4 = 0; d4 < D / 4; ++d4) {
        float4 w = wrow[d4];
        acc += s_g[d4 * 4 + 0] * w.x + s_g[d4 * 4 + 1] * w.y
             + s_g[d4 * 4 + 2] * w.z + s_g[d4 * 4 + 3] * w.w;
    }
    x_ws[(size_t)b * D + e] = acc;
    if (tid == 0) gate_out[b] = has ? 1.0f : 0.0f;
}

// Kernel B v3: 1024 blocks, 4 consecutive t's per block. Wave w owns
// b = w*16..w*16+15. Per t: 16 coalesced float4 src loads (HBM) + 16 x loads
// (L1/L2; x_ws = 64 KB total), then a value-halving butterfly reduce:
// 17 shuffles total for all 16 b's (vs 96 for per-b 6-level reduce).
// After the butterfly, lane L holds the full dot for b0 + (L&15), so
// lanes 0..15 store — 4 t results packed into one coalesced float4 store.
__global__ __launch_bounds__(256) void sim_kernel(
    const float* __restrict__ src, const float* __restrict__ x_ws,
    float* __restrict__ out)
{
    const int wave = threadIdx.x >> 6;
    const int lane = threadIdx.x & 63;
    const int b0   = wave * 16;
    const int t0   = blockIdx.x * 4;

    const float* xrow = x_ws + (size_t)b0 * D + lane * 4;

    float resk[4];
    #pragma unroll
    for (int k = 0; k < 4; ++k) {
        const int t = t0 + k;
        const float* srow = src + (size_t)t * (B * D) + (size_t)b0 * D + lane * 4;

        float a[16];
        #pragma unroll
        for (int i = 0; i < 16; ++i) {
            const float4 sv = *(const float4*)(srow + i * D);
            const float4 xv = *(const float4*)(xrow + i * D);
            a[i] = sv.x * xv.x + sv.y * xv.y + sv.z * xv.z + sv.w * xv.w;
        }

        // Value-halving butterfly: step mask m merges lane-pairs while
        // halving the value count; lane bit selects which index survives.
        float v8[8];
        #pragma unroll
        for (int j = 0; j < 8; ++j) {
            const float xx = a[2 * j], yy = a[2 * j + 1];
            const float send = (lane & 1) ? xx : yy;
            const float recv = __shfl_xor(send, 1, 64);
            v8[j] = ((lane & 1) ? yy : xx) + recv;
        }
        float v4a[4];
        #pragma unroll
        for (int j = 0; j < 4; ++j) {
            const float xx = v8[2 * j], yy = v8[2 * j + 1];
            const float send = (lane & 2) ? xx : yy;
            const float recv = __shfl_xor(send, 2, 64);
            v4a[j] = ((lane & 2) ? yy : xx) + recv;
        }
        float v2a[2];
        #pragma unroll
        for (int j = 0; j < 2; ++j) {
            const float xx = v4a[2 * j], yy = v4a[2 * j + 1];
            const float send = (lane & 4) ? xx : yy;
            const float recv = __shfl_xor(send, 4, 64);
            v2a[j] = ((lane & 4) ? yy : xx) + recv;
        }
        float v1;
        {
            const float xx = v2a[0], yy = v2a[1];
            const float send = (lane & 8) ? xx : yy;
            const float recv = __shfl_xor(send, 8, 64);
            v1 = ((lane & 8) ? yy : xx) + recv;
        }
        v1 += __shfl_xor(v1, 16, 64);
        v1 += __shfl_xor(v1, 32, 64);
        // lane L now holds sum for b0 + (L&15) over all 64 lanes.
        resk[k] = v1;
    }

    if (lane < 16) {
        float4 o;
        o.x = resk[0] * 0.0625f;   // 1/sqrt(256)
        o.y = resk[1] * 0.0625f;
        o.z = resk[2] * 0.0625f;
        o.w = resk[3] * 0.0625f;
        *(float4*)(out + (size_t)(b0 + lane) * T + t0) = o;
    }
}

extern "C" void kernel_launch(void* const* d_in, const int* in_sizes, int n_in,
                              void* d_out, int out_size, void* d_ws, size_t ws_size,
                              hipStream_t stream) {
    const int*   batch_nodes = (const int*)d_in[0];   // [B,T] int32
    const int*   exe         = (const int*)d_in[1];   // [B,T] int32
    const float* src         = (const float*)d_in[2]; // [T,B,D] f32
    const float* graph_dict  = (const float*)d_in[3]; // [GNN_NODES,D] f32
    const float* W0          = (const float*)d_in[4]; // [D,D] f32
    const float* b0          = (const float*)d_in[5]; // [D] f32

    float* out  = (float*)d_out;          // [B*T] sim, then [B] gate
    float* gate = out + (size_t)B * T;
    float* x_ws = (float*)d_ws;           // B*D floats = 64 KB

    prep_kernel<<<B, 256, 0, stream>>>(batch_nodes, exe, graph_dict, W0, b0, x_ws, gate);
    sim_kernel<<<T / 4, 256, 0, stream>>>(src, x_ws, out);
}